// Round 2
// baseline (203.978 us; speedup 1.0000x reference)
//
#include <hip/hip_runtime.h>
#include <stdint.h>

// out[b,s,n] = int32(sum_k x[b,s,k]*w[n,k]) * (scale_i*scale_w[n]) + bias[n]
// Harness materializes integer inputs as int32: x is [M,K] int32 (values in [-128,127]),
// w is [N,K] int32. We pack to int8 in d_ws, then run the int8 MFMA GEMM.
#define M_DIM 8192
#define N_DIM 4096
#define K_DIM 1024

using i32x4 = __attribute__((ext_vector_type(4))) int;

// ---- pack pass: int32 (low byte = value) -> int8, 16 ints per thread ----
__global__ __launch_bounds__(256) void pack_i8(const int* __restrict__ src,
                                               int* __restrict__ dst,   // packed dwords
                                               int n_dwords) {          // = n_ints/4
    int u = blockIdx.x * blockDim.x + threadIdx.x;   // one thread packs 4 dwords
    int base = u * 4;
    if (base >= n_dwords) return;
    const int4* s4 = (const int4*)src;
    int4 o;
    #pragma unroll
    for (int i = 0; i < 4; ++i) {
        int4 v = s4[base + i];   // 4 int32
        int packed = (v.x & 0xFF) | ((v.y & 0xFF) << 8) |
                     ((v.z & 0xFF) << 16) | (v.w << 24);
        ((int*)&o)[i] = packed;
    }
    ((int4*)dst)[u] = o;
}

// async global->LDS, 16B per lane. LDS dest is wave-uniform base + lane*16.
__device__ __forceinline__ void cp16_async(const void* g, void* l) {
    __builtin_amdgcn_global_load_lds(
        (const __attribute__((address_space(1))) void*)g,
        (__attribute__((address_space(3))) void*)l,
        16, 0, 0);
}

// 128x128 tile, BK=64, 256 threads = 4 waves (2x2), 64x64 per wave,
// 4x4 tiles of v_mfma_i32_16x16x64_i8 per wave.
__global__ __launch_bounds__(256, 2) void i8gemm_dequant(
    const int8_t* __restrict__ X,        // [M, K] packed int8
    const int8_t* __restrict__ W,        // [N, K] packed int8
    const float*  __restrict__ scale_i,  // [1]
    const float*  __restrict__ scale_w,  // [N]
    const float*  __restrict__ bias,     // [N]
    float*        __restrict__ out)      // [M, N]
{
    __shared__ int8_t lA[128 * 64];   // 8 KB
    __shared__ int8_t lB[128 * 64];   // 8 KB

    const int t     = threadIdx.x;
    const int lane  = t & 63;
    const int wave  = t >> 6;
    const int waveM = wave >> 1;
    const int waveN = wave & 1;

    const int bm = blockIdx.y * 128;
    const int bn = blockIdx.x * 128;

    i32x4 acc[4][4] = {};

    // staging: chunk c in [0,512): LDS addr c*16; row=c>>2, qlds=c&3,
    // content = logical quad qlog = qlds ^ ((row>>1)&3)  (XOR swizzle)
    const int c0   = t;
    const int row0 = c0 >> 2;
    const int q0   = (c0 & 3) ^ ((row0 >> 1) & 3);
    const int c1   = 256 + t;
    const int row1 = c1 >> 2;
    const int q1   = (c1 & 3) ^ ((row1 >> 1) & 3);

    const int8_t* Asrc0 = X + (size_t)(bm + row0) * K_DIM + q0 * 16;
    const int8_t* Asrc1 = X + (size_t)(bm + row1) * K_DIM + q1 * 16;
    const int8_t* Bsrc0 = W + (size_t)(bn + row0) * K_DIM + q0 * 16;
    const int8_t* Bsrc1 = W + (size_t)(bn + row1) * K_DIM + q1 * 16;

    int8_t* dA0 = lA + (wave * 64) * 16;         // wave-uniform; HW adds lane*16
    int8_t* dA1 = lA + (256 + wave * 64) * 16;
    int8_t* dB0 = lB + (wave * 64) * 16;
    int8_t* dB1 = lB + (256 + wave * 64) * 16;

    // fragment reads: logical (r, q=lane>>4) -> addr r*64 + (q^((r>>1)&3))*16
    int aoff[4], boff[4];
    #pragma unroll
    for (int i = 0; i < 4; ++i) {
        int r = waveM * 64 + i * 16 + (lane & 15);
        int q = (lane >> 4) ^ ((r >> 1) & 3);
        aoff[i] = r * 64 + q * 16;
    }
    #pragma unroll
    for (int j = 0; j < 4; ++j) {
        int r = waveN * 64 + j * 16 + (lane & 15);
        int q = (lane >> 4) ^ ((r >> 1) & 3);
        boff[j] = r * 64 + q * 16;
    }

    for (int k0 = 0; k0 < K_DIM; k0 += 64) {
        cp16_async(Asrc0 + k0, dA0);
        cp16_async(Asrc1 + k0, dA1);
        cp16_async(Bsrc0 + k0, dB0);
        cp16_async(Bsrc1 + k0, dB1);
        __syncthreads();

        i32x4 afrag[4], bfrag[4];
        #pragma unroll
        for (int i = 0; i < 4; ++i) afrag[i] = *(const i32x4*)(lA + aoff[i]);
        #pragma unroll
        for (int j = 0; j < 4; ++j) bfrag[j] = *(const i32x4*)(lB + boff[j]);

        #pragma unroll
        for (int i = 0; i < 4; ++i)
            #pragma unroll
            for (int j = 0; j < 4; ++j)
                acc[i][j] = __builtin_amdgcn_mfma_i32_16x16x64_i8(
                    afrag[i], bfrag[j], acc[i][j], 0, 0, 0);

        __syncthreads();
    }

    // epilogue: C/D layout col=lane&15, row=(lane>>4)*4+reg
    const float si = scale_i[0];
    float s[4], b[4];
    int   ncol[4];
    #pragma unroll
    for (int j = 0; j < 4; ++j) {
        ncol[j] = bn + waveN * 64 + j * 16 + (lane & 15);
        s[j] = si * scale_w[ncol[j]];
        b[j] = bias[ncol[j]];
    }
    #pragma unroll
    for (int i = 0; i < 4; ++i) {
        int mbase = bm + waveM * 64 + i * 16 + ((lane >> 4) * 4);
        #pragma unroll
        for (int r = 0; r < 4; ++r) {
            size_t rowoff = (size_t)(mbase + r) * N_DIM;
            #pragma unroll
            for (int j = 0; j < 4; ++j) {
                out[rowoff + ncol[j]] = (float)acc[i][j][r] * s[j] + b[j];
            }
        }
    }
}

extern "C" void kernel_launch(void* const* d_in, const int* in_sizes, int n_in,
                              void* d_out, int out_size, void* d_ws, size_t ws_size,
                              hipStream_t stream) {
    const int* x32 = (const int*)d_in[0];   // [M,K] int32
    const int* w32 = (const int*)d_in[1];   // [N,K] int32
    const float* si = (const float*)d_in[2];
    const float* sw = (const float*)d_in[3];
    const float* bs = (const float*)d_in[4];
    float* out = (float*)d_out;

    int8_t* Xp = (int8_t*)d_ws;                              // 8 MB
    int8_t* Wp = (int8_t*)d_ws + (size_t)M_DIM * K_DIM;      // 4 MB

    {   // pack X: 8388608 ints -> 2097152 dwords; 4 dwords/thread
        int nd = M_DIM * K_DIM / 4;
        int threads = nd / 4;
        pack_i8<<<threads / 256, 256, 0, stream>>>(x32, (int*)Xp, nd);
    }
    {   // pack W: 4194304 ints -> 1048576 dwords
        int nd = N_DIM * K_DIM / 4;
        int threads = nd / 4;
        pack_i8<<<threads / 256, 256, 0, stream>>>(w32, (int*)Wp, nd);
    }

    dim3 grid(N_DIM / 128, M_DIM / 128);   // 32 x 64 blocks
    i8gemm_dequant<<<grid, 256, 0, stream>>>(Xp, Wp, si, sw, bs, out);
}

// Round 3
// 197.952 us; speedup vs baseline: 1.0304x; 1.0304x over previous
//
#include <hip/hip_runtime.h>
#include <stdint.h>

// out[b,s,n] = int32(sum_k x[b,s,k]*w[n,k]) * (scale_i*scale_w[n]) + bias[n]
// Harness materializes integer inputs as int32: x is [M,K] int32 (values in [-128,127]),
// w is [N,K] int32. Pack to int8 in d_ws, then int8 MFMA GEMM with BK=128 K-tiles.
#define M_DIM 8192
#define N_DIM 4096
#define K_DIM 1024
#define BK    128

using i32x4 = __attribute__((ext_vector_type(4))) int;

// ---- fused pack pass: int32 (low byte) -> int8, 16 ints per thread ----
// blocks [0, 2048): X (8.4M ints); blocks [2048, 3072): W (4.2M ints)
__global__ __launch_bounds__(256) void pack_both(const int* __restrict__ X32,
                                                 const int* __restrict__ W32,
                                                 int* __restrict__ Xp,
                                                 int* __restrict__ Wp) {
    int b = blockIdx.x;
    const int4* s4;
    int4* d4;
    int u;
    if (b < 2048) {            // X: 2097152 packed dwords / 4 per thread
        u  = b * 256 + threadIdx.x;
        s4 = (const int4*)X32;
        d4 = (int4*)Xp;
    } else {                   // W: 1048576 packed dwords / 4 per thread
        u  = (b - 2048) * 256 + threadIdx.x;
        s4 = (const int4*)W32;
        d4 = (int4*)Wp;
    }
    int4 o;
    #pragma unroll
    for (int i = 0; i < 4; ++i) {
        int4 v = s4[u * 4 + i];
        ((int*)&o)[i] = (v.x & 0xFF) | ((v.y & 0xFF) << 8) |
                        ((v.z & 0xFF) << 16) | (v.w << 24);
    }
    d4[u] = o;
}

// async global->LDS, 16B per lane. LDS dest is wave-uniform base + lane*16.
__device__ __forceinline__ void cp16_async(const void* g, void* l) {
    __builtin_amdgcn_global_load_lds(
        (const __attribute__((address_space(1))) void*)g,
        (__attribute__((address_space(3))) void*)l,
        16, 0, 0);
}

// 128x128 tile, BK=128, 256 threads = 4 waves (2x2), 64x64 per wave,
// 4x4 tiles x 2 K-halves of v_mfma_i32_16x16x64_i8 per wave per K-tile.
__global__ __launch_bounds__(256, 2) void i8gemm_dequant(
    const int8_t* __restrict__ X,        // [M, K] packed int8
    const int8_t* __restrict__ W,        // [N, K] packed int8
    const float*  __restrict__ scale_i,  // [1]
    const float*  __restrict__ scale_w,  // [N]
    const float*  __restrict__ bias,     // [N]
    float*        __restrict__ out)      // [M, N]
{
    __shared__ int8_t lA[128 * BK];   // 16 KB
    __shared__ int8_t lB[128 * BK];   // 16 KB

    const int t     = threadIdx.x;
    const int lane  = t & 63;
    const int wave  = t >> 6;
    const int waveM = wave >> 1;
    const int waveN = wave & 1;

    const int bm = blockIdx.y * 128;
    const int bn = blockIdx.x * 128;

    i32x4 acc[4][4] = {};

    // staging: chunk c in [0,1024) per matrix: LDS addr c*16; row=c>>3, qlds=c&7,
    // content = logical quad q = qlds ^ (row&7)  (XOR swizzle over the 8-chunk row)
    const int8_t* Asrc[4];
    const int8_t* Bsrc[4];
    int8_t* dA[4];
    int8_t* dB[4];
    #pragma unroll
    for (int s = 0; s < 4; ++s) {
        int c   = t + 256 * s;
        int row = c >> 3;
        int q   = (c & 7) ^ (row & 7);
        Asrc[s] = X + (size_t)(bm + row) * K_DIM + q * 16;
        Bsrc[s] = W + (size_t)(bn + row) * K_DIM + q * 16;
        dA[s]   = lA + (256 * s + wave * 64) * 16;   // wave-uniform; HW adds lane*16
        dB[s]   = lB + (256 * s + wave * 64) * 16;
    }

    // fragment reads: logical (r, q = h*4 + (lane>>4)) -> addr r*BK + (q^(r&7))*16
    int aoff[2][4], boff[2][4];
    #pragma unroll
    for (int h = 0; h < 2; ++h) {
        #pragma unroll
        for (int i = 0; i < 4; ++i) {
            int r = waveM * 64 + i * 16 + (lane & 15);
            int q = (h * 4 + (lane >> 4)) ^ (r & 7);
            aoff[h][i] = r * BK + q * 16;
        }
        #pragma unroll
        for (int j = 0; j < 4; ++j) {
            int r = waveN * 64 + j * 16 + (lane & 15);
            int q = (h * 4 + (lane >> 4)) ^ (r & 7);
            boff[h][j] = r * BK + q * 16;
        }
    }

    for (int k0 = 0; k0 < K_DIM; k0 += BK) {
        #pragma unroll
        for (int s = 0; s < 4; ++s) {
            cp16_async(Asrc[s] + k0, dA[s]);
            cp16_async(Bsrc[s] + k0, dB[s]);
        }
        __syncthreads();

        i32x4 af[2][4], bf[2][4];
        #pragma unroll
        for (int h = 0; h < 2; ++h) {
            #pragma unroll
            for (int i = 0; i < 4; ++i) af[h][i] = *(const i32x4*)(lA + aoff[h][i]);
            #pragma unroll
            for (int j = 0; j < 4; ++j) bf[h][j] = *(const i32x4*)(lB + boff[h][j]);
        }

        #pragma unroll
        for (int h = 0; h < 2; ++h)
            #pragma unroll
            for (int i = 0; i < 4; ++i)
                #pragma unroll
                for (int j = 0; j < 4; ++j)
                    acc[i][j] = __builtin_amdgcn_mfma_i32_16x16x64_i8(
                        af[h][i], bf[h][j], acc[i][j], 0, 0, 0);

        __syncthreads();
    }

    // epilogue: C/D layout col=lane&15, row=(lane>>4)*4+reg
    const float si = scale_i[0];
    float s[4], b[4];
    int   ncol[4];
    #pragma unroll
    for (int j = 0; j < 4; ++j) {
        ncol[j] = bn + waveN * 64 + j * 16 + (lane & 15);
        s[j] = si * scale_w[ncol[j]];
        b[j] = bias[ncol[j]];
    }
    #pragma unroll
    for (int i = 0; i < 4; ++i) {
        int mbase = bm + waveM * 64 + i * 16 + ((lane >> 4) * 4);
        #pragma unroll
        for (int r = 0; r < 4; ++r) {
            size_t rowoff = (size_t)(mbase + r) * N_DIM;
            #pragma unroll
            for (int j = 0; j < 4; ++j) {
                out[rowoff + ncol[j]] = (float)acc[i][j][r] * s[j] + b[j];
            }
        }
    }
}

extern "C" void kernel_launch(void* const* d_in, const int* in_sizes, int n_in,
                              void* d_out, int out_size, void* d_ws, size_t ws_size,
                              hipStream_t stream) {
    const int* x32 = (const int*)d_in[0];   // [M,K] int32
    const int* w32 = (const int*)d_in[1];   // [N,K] int32
    const float* si = (const float*)d_in[2];
    const float* sw = (const float*)d_in[3];
    const float* bs = (const float*)d_in[4];
    float* out = (float*)d_out;

    int8_t* Xp = (int8_t*)d_ws;                              // 8 MB
    int8_t* Wp = (int8_t*)d_ws + (size_t)M_DIM * K_DIM;      // 4 MB

    // one fused pack launch: 2048 blocks for X + 1024 for W
    pack_both<<<3072, 256, 0, stream>>>(x32, w32, (int*)Xp, (int*)Wp);

    dim3 grid(N_DIM / 128, M_DIM / 128);   // 32 x 64 blocks
    i8gemm_dequant<<<grid, 256, 0, stream>>>(Xp, Wp, si, sw, bs, out);
}